// Round 7
// baseline (108.575 us; speedup 1.0000x reference)
//
#include <hip/hip_runtime.h>
#include <math.h>

// B=8, G=2048, K=32, N=64.
// Algebraic simplification (verified): e_x is constant along the K axis that
// up/down average over => k_anp_x = mean(ff,K) exactly; std_dev/p/nrm/lc/e_x
// branch is dead code. kl = 2*mean(ff,K); the norm over G cancels the 2.
// Everything feeding fourier_B is linear in 1/std => projection on RAW diffs,
// inv applied once at the end (sort order invariant under inv>0).
//
//  k1/k1f : global std(diff, ddof=1) (two-stage double reduce)
//  k2     : per-wave EIGHTH-streamed LDS staging (2 KB granule, double-buf,
//           counted vmcnt, barrier-free), row-keyed 1-bit rotation,
//           68 @ fB(68x32), butterfly-compaction K-reduce, direct M store.
//           LDS 18 KB -> 8 blocks/CU.
//  k3p/k3r: inv_r[b,c] = 1/||M[b,:,c]||_G  (coalesced 2-stage)
//  k3b    : out[b,c,g] = gelu(M*inv_r) - lc_line ; out[b,64+c,g] = lc_line

constexpr int Gg = 2048;

constexpr size_t PART_OFF = 0;       // k1: 2048*2 doubles; k3p: 128*64 f32
constexpr size_t STD_OFF  = 32768;   // 1 float
constexpr size_t INVR_OFF = 33024;   // 512 floats
constexpr size_t M_OFF    = 65536;   // 8*2048*64 floats = 4 MiB

// ---------------- K1: partial sums for global std ----------------
__global__ __launch_bounds__(256) void k1_partial(const float4* __restrict__ knn4,
                                                  const float4* __restrict__ lc4,
                                                  double* __restrict__ part)
{
    int tid  = threadIdx.x;
    int base = blockIdx.x * 256 + tid;
    float4 q[16];
    #pragma unroll
    for (int i = 0; i < 16; ++i) q[i] = knn4[base + i * 524288];
    double s = 0.0, s2 = 0.0;
    #pragma unroll
    for (int i = 0; i < 16; ++i) {
        int idx = base + i * 524288;
        float4 l = lc4[(idx >> 9) * 16 + (idx & 15)];
        float d0 = q[i].x - l.x, d1 = q[i].y - l.y, d2 = q[i].z - l.z, d3 = q[i].w - l.w;
        s += (double)d0; s += (double)d1; s += (double)d2; s += (double)d3;
        s2 = fma((double)d0, (double)d0, s2);
        s2 = fma((double)d1, (double)d1, s2);
        s2 = fma((double)d2, (double)d2, s2);
        s2 = fma((double)d3, (double)d3, s2);
    }
    __shared__ double sh[512];
    sh[tid] = s; sh[256 + tid] = s2;
    __syncthreads();
    for (int off = 128; off > 0; off >>= 1) {
        if (tid < off) { sh[tid] += sh[tid + off]; sh[256 + tid] += sh[256 + tid + off]; }
        __syncthreads();
    }
    if (tid == 0) { part[blockIdx.x * 2] = sh[0]; part[blockIdx.x * 2 + 1] = sh[256]; }
}

__global__ __launch_bounds__(256) void k1_final(const double* __restrict__ part,
                                                float* __restrict__ stdp)
{
    int tid = threadIdx.x;
    double s = 0.0, s2 = 0.0;
    for (int i = tid; i < 2048; i += 256) { s += part[2*i]; s2 += part[2*i+1]; }
    __shared__ double sh[512];
    sh[tid] = s; sh[256 + tid] = s2;
    __syncthreads();
    for (int off = 128; off > 0; off >>= 1) {
        if (tid < off) { sh[tid] += sh[tid + off]; sh[256 + tid] += sh[256 + tid + off]; }
        __syncthreads();
    }
    if (tid == 0) {
        double S = sh[0], S2 = sh[256];
        double Mn = 33554432.0;
        double var = (S2 - S * S / Mn) / (Mn - 1.0);
        stdp[0] = (float)sqrt(var);
    }
}

// ---------------- K2: main fused kernel ----------------
// Wave w owns rows 64w..64w+63. Eighth e = 2 chunks (32 B) of each row,
// double-buffered in qbuf[e&1][w] (2 KB/wave region). Rotation keyed on row:
// slot t of row r holds chunk 2e + (t ^ k(r)), k(r) = (r>>2)&1.
//   writer gll#0 lane ls: row = ls>>1 (0..31), t = ls&1, src chunk = t^((ls>>3)&1)
//   writer gll#1 lane ls: row = 32+(ls>>1), same swizzle formula
//   reader row l, sub jj: slot = jj ^ ((l>>2)&1)
// Verified by hand at (r5,e3,jj1),(r12,e0,jj0),(r40,e2,jj1). 16-lane read
// phase: 2 lanes per bank-quad = free. Sources 32-B contiguous per row pair.
__global__ __launch_bounds__(256, 8) void k2_main(const float* __restrict__ knn,
                                                  const float* __restrict__ lc,
                                                  const float* __restrict__ fB,
                                                  const float* __restrict__ stdp,
                                                  float* __restrict__ M)
{
    __shared__ float4 qbuf[2][4][128];  // [buf][wave][row*2 + slot]  16 KB
    __shared__ float4 lcs[8][16];       // 2 KB

    const int tid = threadIdx.x;
    const int w   = tid >> 6;
    const int l   = tid & 63;
    const int grp = tid >> 5;
    const int key = (l >> 2) & 1;       // reader rotation key (row-keyed)

    const char* gbase = (const char*)knn + (size_t)blockIdx.x * 65536;
    // writer per-lane source (gll#0): row ls>>1, chunk (ls&1)^((ls>>3)&1)
    const char* srcA = gbase + (size_t)w * 16384
                     + (size_t)(l >> 1) * 256
                     + (size_t)(((l & 1) ^ ((l >> 3) & 1)) * 16);
    const char* srcB = srcA + 8192;     // rows 32..63, same swizzle

    float4 lreg = make_float4(0.f, 0.f, 0.f, 0.f);
    if (l < 32)
        lreg = ((const float4*)lc)[(size_t)(blockIdx.x * 8 + 2 * w + (l >> 4)) * 16 + (l & 15)];

#define STAGE(e, buf)                                                          \
    {                                                                          \
        __builtin_amdgcn_global_load_lds((const void*)(srcA + (e) * 32),       \
            (void*)&qbuf[buf][w][ 0], 16, 0, 0);                               \
        __builtin_amdgcn_global_load_lds((const void*)(srcB + (e) * 32),       \
            (void*)&qbuf[buf][w][64], 16, 0, 0);                               \
    }

    STAGE(0, 0)
    STAGE(1, 1)
    if (l < 32) lcs[2 * w + (l >> 4)][l & 15] = lreg;   // wave-private

    const float inv = 1.0f / (stdp[0] + 1e-5f);

    float acc[32];
    #pragma unroll
    for (int c = 0; c < 32; ++c) acc[c] = 0.0f;
    float dot = 0.0f;
    float kn0 = 0, kn1 = 0, kn2 = 0, ln0 = 0, ln1 = 0, ln2 = 0;

#define VMWAIT(n)  asm volatile("s_waitcnt vmcnt(" #n ")" ::: "memory");      \
                   __builtin_amdgcn_sched_barrier(0);
#define LKWAIT     asm volatile("s_waitcnt lgkmcnt(0)" ::: "memory");         \
                   __builtin_amdgcn_sched_barrier(0);

#define CHUNK(e, jj)                                                          \
    {                                                                         \
        float4 qv = qbuf[(e) & 1][w][l * 2 + ((jj) ^ key)];                   \
        float4 lv = lcs[grp][(e) * 2 + (jj)];                                 \
        float e0 = qv.x - lv.x, e1 = qv.y - lv.y,                             \
              e2 = qv.z - lv.z, e3 = qv.w - lv.w;                             \
        if ((e) == 0 && (jj) == 0) {                                          \
            kn0 = e0; kn1 = e1; kn2 = e2;                                     \
            ln0 = lv.x; ln1 = lv.y; ln2 = lv.z;                               \
        }                                                                     \
        dot = fmaf(e0, lv.x, dot); dot = fmaf(e1, lv.y, dot);                 \
        dot = fmaf(e2, lv.z, dot); dot = fmaf(e3, lv.w, dot);                 \
        const float* fr = fB + ((e) * 2 + (jj)) * 128;                        \
        _Pragma("unroll")                                                     \
        for (int c = 0; c < 32; ++c) acc[c] = fmaf(e0, fr[c],      acc[c]);   \
        _Pragma("unroll")                                                     \
        for (int c = 0; c < 32; ++c) acc[c] = fmaf(e1, fr[32 + c], acc[c]);   \
        _Pragma("unroll")                                                     \
        for (int c = 0; c < 32; ++c) acc[c] = fmaf(e2, fr[64 + c], acc[c]);   \
        _Pragma("unroll")                                                     \
        for (int c = 0; c < 32; ++c) acc[c] = fmaf(e3, fr[96 + c], acc[c]);   \
    }

    VMWAIT(2)  CHUNK(0, 0) CHUNK(0, 1)
    LKWAIT     STAGE(2, 0)
    VMWAIT(2)  CHUNK(1, 0) CHUNK(1, 1)
    LKWAIT     STAGE(3, 1)
    VMWAIT(2)  CHUNK(2, 0) CHUNK(2, 1)
    LKWAIT     STAGE(4, 0)
    VMWAIT(2)  CHUNK(3, 0) CHUNK(3, 1)
    LKWAIT     STAGE(5, 1)
    VMWAIT(2)  CHUNK(4, 0) CHUNK(4, 1)
    LKWAIT     STAGE(6, 0)
    VMWAIT(2)  CHUNK(5, 0) CHUNK(5, 1)
    LKWAIT     STAGE(7, 1)
    VMWAIT(2)  CHUNK(6, 0) CHUNK(6, 1)
    VMWAIT(0)  CHUNK(7, 0) CHUNK(7, 1)

#undef CHUNK
#undef STAGE
#undef VMWAIT
#undef LKWAIT

    // descending sort3 of raw d[0:3] and lc[0:3] (inv>0 preserves order)
    float a0 = kn0, a1 = kn1, a2 = kn2;
    float b0 = ln0, b1 = ln1, b2 = ln2;
    float t;
    if (a0 < a1) { t = a0; a0 = a1; a1 = t; }
    if (a1 < a2) { t = a1; a1 = a2; a2 = t; }
    if (a0 < a1) { t = a0; a0 = a1; a1 = t; }
    if (b0 < b1) { t = b0; b0 = b1; b1 = t; }
    if (b1 < b2) { t = b1; b1 = b2; b2 = t; }
    if (b0 < b1) { t = b0; b0 = b1; b1 = t; }

    float cr0 = a1 * b2 - a2 * b1;     // raw cross; inv scales through
    float cr1 = a2 * b0 - a0 * b2;
    float cr2 = a0 * b1 - a1 * b0;
    {
        const float* fr = fB + 64 * 32;
        #pragma unroll
        for (int c = 0; c < 32; ++c) acc[c] = fmaf(cr0, fr[c],      acc[c]);
        #pragma unroll
        for (int c = 0; c < 32; ++c) acc[c] = fmaf(cr1, fr[32 + c], acc[c]);
        #pragma unroll
        for (int c = 0; c < 32; ++c) acc[c] = fmaf(cr2, fr[64 + c], acc[c]);
        #pragma unroll
        for (int c = 0; c < 32; ++c) acc[c] = fmaf(dot, fr[96 + c], acc[c]);
    }

    // phase = inv*acc revolutions; exact reduction r = a - rint(a); hw sin/cos
    float vs[32], vc[32];
    #pragma unroll
    for (int c = 0; c < 32; ++c) {
        float a = acc[c] * inv;
        float r = a - rintf(a);
        vs[c] = __builtin_amdgcn_sinf(r);
        vc[c] = __builtin_amdgcn_cosf(r);
    }

    // butterfly-compaction reduce over the 32 K-lanes; lane ends holding the
    // full K-sum for column c = lane&31.
    float s1[16], c1[16];
    #pragma unroll
    for (int j = 0; j < 16; ++j) {
        float ea = vs[2*j]   + __shfl_xor(vs[2*j],   1);
        float eb = vs[2*j+1] + __shfl_xor(vs[2*j+1], 1);
        s1[j] = (tid & 1) ? eb : ea;
        float fa = vc[2*j]   + __shfl_xor(vc[2*j],   1);
        float fb = vc[2*j+1] + __shfl_xor(vc[2*j+1], 1);
        c1[j] = (tid & 1) ? fb : fa;
    }
    float s2[8], c2[8];
    #pragma unroll
    for (int j = 0; j < 8; ++j) {
        float ea = s1[2*j]   + __shfl_xor(s1[2*j],   2);
        float eb = s1[2*j+1] + __shfl_xor(s1[2*j+1], 2);
        s2[j] = (tid & 2) ? eb : ea;
        float fa = c1[2*j]   + __shfl_xor(c1[2*j],   2);
        float fb = c1[2*j+1] + __shfl_xor(c1[2*j+1], 2);
        c2[j] = (tid & 2) ? fb : fa;
    }
    float s3[4], c3[4];
    #pragma unroll
    for (int j = 0; j < 4; ++j) {
        float ea = s2[2*j]   + __shfl_xor(s2[2*j],   4);
        float eb = s2[2*j+1] + __shfl_xor(s2[2*j+1], 4);
        s3[j] = (tid & 4) ? eb : ea;
        float fa = c2[2*j]   + __shfl_xor(c2[2*j],   4);
        float fb = c2[2*j+1] + __shfl_xor(c2[2*j+1], 4);
        c3[j] = (tid & 4) ? fb : fa;
    }
    float s4[2], c4[2];
    #pragma unroll
    for (int j = 0; j < 2; ++j) {
        float ea = s3[2*j]   + __shfl_xor(s3[2*j],   8);
        float eb = s3[2*j+1] + __shfl_xor(s3[2*j+1], 8);
        s4[j] = (tid & 8) ? eb : ea;
        float fa = c3[2*j]   + __shfl_xor(c3[2*j],   8);
        float fb = c3[2*j+1] + __shfl_xor(c3[2*j+1], 8);
        c4[j] = (tid & 8) ? fb : fa;
    }
    float ea = s4[0] + __shfl_xor(s4[0], 16);
    float eb = s4[1] + __shfl_xor(s4[1], 16);
    float ssum = ((tid & 16) ? eb : ea) * (1.0f / 32.0f);
    float fa = c4[0] + __shfl_xor(c4[0], 16);
    float fb = c4[1] + __shfl_xor(c4[1], 16);
    float csum = ((tid & 16) ? fb : fa) * (1.0f / 32.0f);

    const int cc   = tid & 31;
    const int mrow = blockIdx.x * 8 + grp;      // = b*G+g
    M[(size_t)mrow * 64 + cc]      = ssum;
    M[(size_t)mrow * 64 + 32 + cc] = csum;
}

// ---------------- K3p: per-(b,gb) partial ssq over 128 g, coalesced ----------------
__global__ __launch_bounds__(256) void k3_part(const float* __restrict__ M,
                                               float* __restrict__ part2)
{
    int blk = blockIdx.x;                 // b*16 + gb
    int b = blk >> 4, gb = blk & 15;
    int t = threadIdx.x;
    int c = t & 63, gs = t >> 6;          // 0..3
    const float* base = M + ((size_t)(b * Gg + gb * 128 + gs)) * 64 + c;
    float ss = 0.0f;
    #pragma unroll
    for (int i = 0; i < 32; ++i) {        // g = gb*128 + gs + 4*i
        float v = base[(size_t)i * 256];
        ss = fmaf(v, v, ss);
    }
    __shared__ float sh[256];
    sh[t] = ss;
    __syncthreads();
    if (t < 64) part2[blk * 64 + t] = sh[t] + sh[t + 64] + sh[t + 128] + sh[t + 192];
}

__global__ __launch_bounds__(64) void k3_rfin(const float* __restrict__ part2,
                                              float* __restrict__ invr)
{
    int b = blockIdx.x, c = threadIdx.x;
    float s = 0.0f;
    #pragma unroll
    for (int gb = 0; gb < 16; ++gb) s += part2[(b * 16 + gb) * 64 + c];
    invr[b * 64 + c] = 1.0f / sqrtf(s);
}

// ---------------- K3b: finalize ----------------
__global__ __launch_bounds__(256) void k3_final(const float* __restrict__ M,
                                                const float* __restrict__ lc,
                                                const float* __restrict__ invr,
                                                float* __restrict__ out)
{
    __shared__ float mt[64][65];
    __shared__ float lt[64][65];
    __shared__ float ir[64];
    __shared__ float iln[64];
    int tid = threadIdx.x;
    int b  = blockIdx.x >> 5;
    int g0 = (blockIdx.x & 31) * 64;
    if (tid < 64) ir[tid] = invr[b * 64 + tid];
    const float* Mb = M  + ((size_t)(b * Gg + g0)) * 64;
    const float* Lb = lc + ((size_t)(b * Gg + g0)) * 64;
    #pragma unroll
    for (int i = 0; i < 4; ++i) {
        int f = i * 1024 + tid * 4;
        int r = f >> 6, col = f & 63;
        float4 mv = *(const float4*)(Mb + f);
        float4 lv = *(const float4*)(Lb + f);
        mt[r][col] = mv.x; mt[r][col+1] = mv.y; mt[r][col+2] = mv.z; mt[r][col+3] = mv.w;
        lt[r][col] = lv.x; lt[r][col+1] = lv.y; lt[r][col+2] = lv.z; lt[r][col+3] = lv.w;
    }
    __syncthreads();
    if (tid < 64) {
        float ss = 0.0f;
        #pragma unroll
        for (int c = 0; c < 64; ++c) { float v = lt[tid][c]; ss = fmaf(v, v, ss); }
        iln[tid] = 1.0f / sqrtf(ss);
    }
    __syncthreads();
    int gl = tid & 63;
    int c0 = tid >> 6;                    // 0..3, wave-uniform
    float il = iln[gl];
    int obase = (b * 128) * Gg + g0 + gl;
    #pragma unroll
    for (int i = 0; i < 16; ++i) {
        int c = c0 + i * 4;
        float lcl = lt[gl][c] * il;
        float x = mt[gl][c] * ir[c];
        float kl = 0.5f * x * (1.0f + erff(x * 0.70710678118654752f));
        out[obase + c * Gg]        = kl - lcl;   // line_element
        out[obase + (c + 64) * Gg] = lcl;        // lc_line
    }
}

extern "C" void kernel_launch(void* const* d_in, const int* in_sizes, int n_in,
                              void* d_out, int out_size, void* d_ws, size_t ws_size,
                              hipStream_t stream)
{
    (void)in_sizes; (void)n_in; (void)out_size; (void)ws_size;
    const float* lc  = (const float*)d_in[0];   // (8,2048,64)
    const float* knn = (const float*)d_in[1];   // (8,2048,32,64)
    const float* fB  = (const float*)d_in[2];   // (68,32)
    float* out = (float*)d_out;                 // (8,128,2048) f32
    char* ws = (char*)d_ws;
    double* part  = (double*)(ws + PART_OFF);
    float*  part2 = (float*)(ws + PART_OFF);
    float*  stdp  = (float*)(ws + STD_OFF);
    float*  invr  = (float*)(ws + INVR_OFF);
    float*  M     = (float*)(ws + M_OFF);

    hipLaunchKernelGGL(k1_partial, dim3(2048), dim3(256), 0, stream,
                       (const float4*)knn, (const float4*)lc, part);
    hipLaunchKernelGGL(k1_final, dim3(1), dim3(256), 0, stream, part, stdp);
    hipLaunchKernelGGL(k2_main, dim3(2048), dim3(256), 0, stream,
                       knn, lc, fB, stdp, M);
    hipLaunchKernelGGL(k3_part, dim3(128), dim3(256), 0, stream, M, part2);
    hipLaunchKernelGGL(k3_rfin, dim3(8), dim3(64), 0, stream, part2, invr);
    hipLaunchKernelGGL(k3_final, dim3(256), dim3(256), 0, stream, M, lc, invr, out);
}

// Round 8
// 100.728 us; speedup vs baseline: 1.0779x; 1.0779x over previous
//
#include <hip/hip_runtime.h>
#include <math.h>

// B=8, G=2048, K=32, N=64.
// Algebraic simplification (verified): e_x is constant along the K axis that
// up/down average over => k_anp_x = mean(ff,K) exactly; std_dev/p/nrm/lc/e_x
// branch is dead code. kl = 2*mean(ff,K); the norm over G cancels the 2.
// Everything feeding fourier_B is linear in 1/std => projection on RAW diffs,
// inv applied once at the end (sort order invariant under inv>0).
//
//  k1/k1f : global std(diff, ddof=1) (two-stage double reduce)
//  k2     : per-wave quarter-streamed LDS staging (64-B granule, double-buf,
//           counted vmcnt ONLY — no lgkmcnt drains, no sched fences),
//           row-keyed rotation, 68 @ fB(68x32) via v_pk_fma_f32 (float2),
//           butterfly-compaction K-reduce, direct M store.
//  k3p/k3r: inv_r[b,c] = 1/||M[b,:,c]||_G  (coalesced 2-stage)
//  k3b    : out[b,c,g] = gelu(M*inv_r) - lc_line ; out[b,64+c,g] = lc_line

constexpr int Gg = 2048;

typedef float v2f __attribute__((ext_vector_type(2)));

constexpr size_t PART_OFF = 0;       // k1: 2048*2 doubles; k3p: 128*64 f32
constexpr size_t STD_OFF  = 32768;   // 1 float
constexpr size_t INVR_OFF = 33024;   // 512 floats
constexpr size_t M_OFF    = 65536;   // 8*2048*64 floats = 4 MiB

// ---------------- K1: partial sums for global std ----------------
__global__ __launch_bounds__(256) void k1_partial(const float4* __restrict__ knn4,
                                                  const float4* __restrict__ lc4,
                                                  double* __restrict__ part)
{
    int tid  = threadIdx.x;
    int base = blockIdx.x * 256 + tid;
    float4 q[16];
    #pragma unroll
    for (int i = 0; i < 16; ++i) q[i] = knn4[base + i * 524288];
    double s = 0.0, s2 = 0.0;
    #pragma unroll
    for (int i = 0; i < 16; ++i) {
        int idx = base + i * 524288;
        float4 l = lc4[(idx >> 9) * 16 + (idx & 15)];
        float d0 = q[i].x - l.x, d1 = q[i].y - l.y, d2 = q[i].z - l.z, d3 = q[i].w - l.w;
        s += (double)d0; s += (double)d1; s += (double)d2; s += (double)d3;
        s2 = fma((double)d0, (double)d0, s2);
        s2 = fma((double)d1, (double)d1, s2);
        s2 = fma((double)d2, (double)d2, s2);
        s2 = fma((double)d3, (double)d3, s2);
    }
    __shared__ double sh[512];
    sh[tid] = s; sh[256 + tid] = s2;
    __syncthreads();
    for (int off = 128; off > 0; off >>= 1) {
        if (tid < off) { sh[tid] += sh[tid + off]; sh[256 + tid] += sh[256 + tid + off]; }
        __syncthreads();
    }
    if (tid == 0) { part[blockIdx.x * 2] = sh[0]; part[blockIdx.x * 2 + 1] = sh[256]; }
}

__global__ __launch_bounds__(256) void k1_final(const double* __restrict__ part,
                                                float* __restrict__ stdp)
{
    int tid = threadIdx.x;
    double s = 0.0, s2 = 0.0;
    for (int i = tid; i < 2048; i += 256) { s += part[2*i]; s2 += part[2*i+1]; }
    __shared__ double sh[512];
    sh[tid] = s; sh[256 + tid] = s2;
    __syncthreads();
    for (int off = 128; off > 0; off >>= 1) {
        if (tid < off) { sh[tid] += sh[tid + off]; sh[256 + tid] += sh[256 + tid + off]; }
        __syncthreads();
    }
    if (tid == 0) {
        double S = sh[0], S2 = sh[256];
        double Mn = 33554432.0;
        double var = (S2 - S * S / Mn) / (Mn - 1.0);
        stdp[0] = (float)sqrt(var);
    }
}

// ---------------- K2: main fused kernel ----------------
// Wave w owns rows 64w..64w+63. Quarter q = 4 chunks (64 B) of each row,
// double-buffered in qbuf[q&1] (4 KB/wave region). Rotation keyed on row:
// slot t of row r holds chunk (t + k)&3 with k = (r>>1)&3  (round-6 verified).
//   writer lane ls: row = ls>>2, slot = ls&3, source chunk = ((ls&3)+((ls>>3)&3))&3
//   reader row l, chunk jj: slot = (jj - ((l>>1)&3)) & 3
// Counted vmcnt only; WAR on buffers is safe by in-order issue (the FMAs'
// compiler-inserted lgkmcnt waits retire the ds_reads before the next gll
// can issue) and VMWAIT's memory clobber blocks compile-time reordering.
__global__ __launch_bounds__(256, 4) void k2_main(const float* __restrict__ knn,
                                                  const float* __restrict__ lc,
                                                  const float* __restrict__ fB,
                                                  const float* __restrict__ stdp,
                                                  float* __restrict__ M)
{
    __shared__ float4 qbuf[2][1024];   // [buf][w*256 + row*4 + slot]  32 KB
    __shared__ float4 lcs[8][16];      // 2 KB

    const int tid = threadIdx.x;
    const int w   = tid >> 6;
    const int l   = tid & 63;
    const int grp = tid >> 5;
    const int key = (l >> 1) & 3;      // reader rotation key (row-keyed)

    const char* gbase = (const char*)knn + (size_t)blockIdx.x * 65536;
    const char* wsrc  = gbase + (size_t)w * 16384
                      + (size_t)(l >> 2) * 256
                      + (size_t)((((l & 3) + ((l >> 3) & 3)) & 3) * 16);

    float4 lreg = make_float4(0.f, 0.f, 0.f, 0.f);
    if (l < 32)
        lreg = ((const float4*)lc)[(size_t)(blockIdx.x * 8 + 2 * w + (l >> 4)) * 16 + (l & 15)];

#define STAGE(q, buf)                                                          \
    {                                                                          \
        __builtin_amdgcn_global_load_lds((const void*)(wsrc + (q) * 64 +     0),\
            (void*)&qbuf[buf][w * 256 +   0], 16, 0, 0);                       \
        __builtin_amdgcn_global_load_lds((const void*)(wsrc + (q) * 64 +  4096),\
            (void*)&qbuf[buf][w * 256 +  64], 16, 0, 0);                       \
        __builtin_amdgcn_global_load_lds((const void*)(wsrc + (q) * 64 +  8192),\
            (void*)&qbuf[buf][w * 256 + 128], 16, 0, 0);                       \
        __builtin_amdgcn_global_load_lds((const void*)(wsrc + (q) * 64 + 12288),\
            (void*)&qbuf[buf][w * 256 + 192], 16, 0, 0);                       \
    }

    STAGE(0, 0)
    STAGE(1, 1)
    if (l < 32) lcs[2 * w + (l >> 4)][l & 15] = lreg;   // wave-private

    const float inv = 1.0f / (stdp[0] + 1e-5f);

    v2f acc2[16];
    #pragma unroll
    for (int c = 0; c < 16; ++c) acc2[c] = (v2f){0.0f, 0.0f};
    float dot = 0.0f;
    float kn0 = 0, kn1 = 0, kn2 = 0, ln0 = 0, ln1 = 0, ln2 = 0;

#define VMWAIT(n)  asm volatile("s_waitcnt vmcnt(" #n ")" ::: "memory");

#define CHUNK(q, jj)                                                          \
    {                                                                         \
        float4 qv = qbuf[(q) & 1][w * 256 + l * 4 + (((jj) - key) & 3)];      \
        float4 lv = lcs[grp][(q) * 4 + (jj)];                                 \
        float e0 = qv.x - lv.x, e1 = qv.y - lv.y,                             \
              e2 = qv.z - lv.z, e3 = qv.w - lv.w;                             \
        if ((q) == 0 && (jj) == 0) {                                          \
            kn0 = e0; kn1 = e1; kn2 = e2;                                     \
            ln0 = lv.x; ln1 = lv.y; ln2 = lv.z;                               \
        }                                                                     \
        dot = fmaf(e0, lv.x, dot); dot = fmaf(e1, lv.y, dot);                 \
        dot = fmaf(e2, lv.z, dot); dot = fmaf(e3, lv.w, dot);                 \
        const v2f* fr2 = (const v2f*)(fB + ((q) * 4 + (jj)) * 128);           \
        v2f ev0 = (v2f){e0, e0}, ev1 = (v2f){e1, e1};                         \
        v2f ev2 = (v2f){e2, e2}, ev3 = (v2f){e3, e3};                         \
        _Pragma("unroll")                                                     \
        for (int c = 0; c < 16; ++c)                                          \
            acc2[c] = __builtin_elementwise_fma(ev0, fr2[c],      acc2[c]);   \
        _Pragma("unroll")                                                     \
        for (int c = 0; c < 16; ++c)                                          \
            acc2[c] = __builtin_elementwise_fma(ev1, fr2[16 + c], acc2[c]);   \
        _Pragma("unroll")                                                     \
        for (int c = 0; c < 16; ++c)                                          \
            acc2[c] = __builtin_elementwise_fma(ev2, fr2[32 + c], acc2[c]);   \
        _Pragma("unroll")                                                     \
        for (int c = 0; c < 16; ++c)                                          \
            acc2[c] = __builtin_elementwise_fma(ev3, fr2[48 + c], acc2[c]);   \
    }

    VMWAIT(4)                                   // quarter 0 landed
    CHUNK(0, 0) CHUNK(0, 1) CHUNK(0, 2) CHUNK(0, 3)
    STAGE(2, 0)
    VMWAIT(4)                                   // quarter 1 landed
    CHUNK(1, 0) CHUNK(1, 1) CHUNK(1, 2) CHUNK(1, 3)
    STAGE(3, 1)
    VMWAIT(4)                                   // quarter 2 landed
    CHUNK(2, 0) CHUNK(2, 1) CHUNK(2, 2) CHUNK(2, 3)
    VMWAIT(0)                                   // quarter 3 landed
    CHUNK(3, 0) CHUNK(3, 1) CHUNK(3, 2) CHUNK(3, 3)

#undef CHUNK
#undef STAGE
#undef VMWAIT

    // descending sort3 of raw d[0:3] and lc[0:3] (inv>0 preserves order)
    float a0 = kn0, a1 = kn1, a2 = kn2;
    float b0 = ln0, b1 = ln1, b2 = ln2;
    float t;
    if (a0 < a1) { t = a0; a0 = a1; a1 = t; }
    if (a1 < a2) { t = a1; a1 = a2; a2 = t; }
    if (a0 < a1) { t = a0; a0 = a1; a1 = t; }
    if (b0 < b1) { t = b0; b0 = b1; b1 = t; }
    if (b1 < b2) { t = b1; b1 = b2; b2 = t; }
    if (b0 < b1) { t = b0; b0 = b1; b1 = t; }

    float cr0 = a1 * b2 - a2 * b1;     // raw cross; inv scales through
    float cr1 = a2 * b0 - a0 * b2;
    float cr2 = a0 * b1 - a1 * b0;
    {
        const v2f* fr2 = (const v2f*)(fB + 64 * 32);
        v2f ev0 = (v2f){cr0, cr0}, ev1 = (v2f){cr1, cr1};
        v2f ev2 = (v2f){cr2, cr2}, ev3 = (v2f){dot, dot};
        #pragma unroll
        for (int c = 0; c < 16; ++c)
            acc2[c] = __builtin_elementwise_fma(ev0, fr2[c],      acc2[c]);
        #pragma unroll
        for (int c = 0; c < 16; ++c)
            acc2[c] = __builtin_elementwise_fma(ev1, fr2[16 + c], acc2[c]);
        #pragma unroll
        for (int c = 0; c < 16; ++c)
            acc2[c] = __builtin_elementwise_fma(ev2, fr2[32 + c], acc2[c]);
        #pragma unroll
        for (int c = 0; c < 16; ++c)
            acc2[c] = __builtin_elementwise_fma(ev3, fr2[48 + c], acc2[c]);
    }

    // phase = inv*acc revolutions; exact reduction r = a - rint(a); hw sin/cos
    const float* acc = (const float*)acc2;      // acc[i] = column i
    float vs[32], vc[32];
    #pragma unroll
    for (int c = 0; c < 32; ++c) {
        float a = acc[c] * inv;
        float r = a - rintf(a);
        vs[c] = __builtin_amdgcn_sinf(r);
        vc[c] = __builtin_amdgcn_cosf(r);
    }

    // butterfly-compaction reduce over the 32 K-lanes; lane ends holding the
    // full K-sum for column c = lane&31.
    float s1[16], c1[16];
    #pragma unroll
    for (int j = 0; j < 16; ++j) {
        float ea = vs[2*j]   + __shfl_xor(vs[2*j],   1);
        float eb = vs[2*j+1] + __shfl_xor(vs[2*j+1], 1);
        s1[j] = (tid & 1) ? eb : ea;
        float fa = vc[2*j]   + __shfl_xor(vc[2*j],   1);
        float fb = vc[2*j+1] + __shfl_xor(vc[2*j+1], 1);
        c1[j] = (tid & 1) ? fb : fa;
    }
    float s2[8], c2[8];
    #pragma unroll
    for (int j = 0; j < 8; ++j) {
        float ea = s1[2*j]   + __shfl_xor(s1[2*j],   2);
        float eb = s1[2*j+1] + __shfl_xor(s1[2*j+1], 2);
        s2[j] = (tid & 2) ? eb : ea;
        float fa = c1[2*j]   + __shfl_xor(c1[2*j],   2);
        float fb = c1[2*j+1] + __shfl_xor(c1[2*j+1], 2);
        c2[j] = (tid & 2) ? fb : fa;
    }
    float s3[4], c3[4];
    #pragma unroll
    for (int j = 0; j < 4; ++j) {
        float ea = s2[2*j]   + __shfl_xor(s2[2*j],   4);
        float eb = s2[2*j+1] + __shfl_xor(s2[2*j+1], 4);
        s3[j] = (tid & 4) ? eb : ea;
        float fa = c2[2*j]   + __shfl_xor(c2[2*j],   4);
        float fb = c2[2*j+1] + __shfl_xor(c2[2*j+1], 4);
        c3[j] = (tid & 4) ? fb : fa;
    }
    float s4[2], c4[2];
    #pragma unroll
    for (int j = 0; j < 2; ++j) {
        float ea = s3[2*j]   + __shfl_xor(s3[2*j],   8);
        float eb = s3[2*j+1] + __shfl_xor(s3[2*j+1], 8);
        s4[j] = (tid & 8) ? eb : ea;
        float fa = c3[2*j]   + __shfl_xor(c3[2*j],   8);
        float fb = c3[2*j+1] + __shfl_xor(c3[2*j+1], 8);
        c4[j] = (tid & 8) ? fb : fa;
    }
    float ea = s4[0] + __shfl_xor(s4[0], 16);
    float eb = s4[1] + __shfl_xor(s4[1], 16);
    float ssum = ((tid & 16) ? eb : ea) * (1.0f / 32.0f);
    float fa = c4[0] + __shfl_xor(c4[0], 16);
    float fb = c4[1] + __shfl_xor(c4[1], 16);
    float csum = ((tid & 16) ? fb : fa) * (1.0f / 32.0f);

    const int cc   = tid & 31;
    const int mrow = blockIdx.x * 8 + grp;      // = b*G+g
    M[(size_t)mrow * 64 + cc]      = ssum;
    M[(size_t)mrow * 64 + 32 + cc] = csum;
}

// ---------------- K3p: per-(b,gb) partial ssq over 128 g, coalesced ----------------
__global__ __launch_bounds__(256) void k3_part(const float* __restrict__ M,
                                               float* __restrict__ part2)
{
    int blk = blockIdx.x;                 // b*16 + gb
    int b = blk >> 4, gb = blk & 15;
    int t = threadIdx.x;
    int c = t & 63, gs = t >> 6;          // 0..3
    const float* base = M + ((size_t)(b * Gg + gb * 128 + gs)) * 64 + c;
    float ss = 0.0f;
    #pragma unroll
    for (int i = 0; i < 32; ++i) {        // g = gb*128 + gs + 4*i
        float v = base[(size_t)i * 256];
        ss = fmaf(v, v, ss);
    }
    __shared__ float sh[256];
    sh[t] = ss;
    __syncthreads();
    if (t < 64) part2[blk * 64 + t] = sh[t] + sh[t + 64] + sh[t + 128] + sh[t + 192];
}

__global__ __launch_bounds__(64) void k3_rfin(const float* __restrict__ part2,
                                              float* __restrict__ invr)
{
    int b = blockIdx.x, c = threadIdx.x;
    float s = 0.0f;
    #pragma unroll
    for (int gb = 0; gb < 16; ++gb) s += part2[(b * 16 + gb) * 64 + c];
    invr[b * 64 + c] = 1.0f / sqrtf(s);
}

// ---------------- K3b: finalize ----------------
__global__ __launch_bounds__(256) void k3_final(const float* __restrict__ M,
                                                const float* __restrict__ lc,
                                                const float* __restrict__ invr,
                                                float* __restrict__ out)
{
    __shared__ float mt[64][65];
    __shared__ float lt[64][65];
    __shared__ float ir[64];
    __shared__ float iln[64];
    int tid = threadIdx.x;
    int b  = blockIdx.x >> 5;
    int g0 = (blockIdx.x & 31) * 64;
    if (tid < 64) ir[tid] = invr[b * 64 + tid];
    const float* Mb = M  + ((size_t)(b * Gg + g0)) * 64;
    const float* Lb = lc + ((size_t)(b * Gg + g0)) * 64;
    #pragma unroll
    for (int i = 0; i < 4; ++i) {
        int f = i * 1024 + tid * 4;
        int r = f >> 6, col = f & 63;
        float4 mv = *(const float4*)(Mb + f);
        float4 lv = *(const float4*)(Lb + f);
        mt[r][col] = mv.x; mt[r][col+1] = mv.y; mt[r][col+2] = mv.z; mt[r][col+3] = mv.w;
        lt[r][col] = lv.x; lt[r][col+1] = lv.y; lt[r][col+2] = lv.z; lt[r][col+3] = lv.w;
    }
    __syncthreads();
    if (tid < 64) {
        float ss = 0.0f;
        #pragma unroll
        for (int c = 0; c < 64; ++c) { float v = lt[tid][c]; ss = fmaf(v, v, ss); }
        iln[tid] = 1.0f / sqrtf(ss);
    }
    __syncthreads();
    int gl = tid & 63;
    int c0 = tid >> 6;                    // 0..3, wave-uniform
    float il = iln[gl];
    int obase = (b * 128) * Gg + g0 + gl;
    #pragma unroll
    for (int i = 0; i < 16; ++i) {
        int c = c0 + i * 4;
        float lcl = lt[gl][c] * il;
        float x = mt[gl][c] * ir[c];
        float kl = 0.5f * x * (1.0f + erff(x * 0.70710678118654752f));
        out[obase + c * Gg]        = kl - lcl;   // line_element
        out[obase + (c + 64) * Gg] = lcl;        // lc_line
    }
}

extern "C" void kernel_launch(void* const* d_in, const int* in_sizes, int n_in,
                              void* d_out, int out_size, void* d_ws, size_t ws_size,
                              hipStream_t stream)
{
    (void)in_sizes; (void)n_in; (void)out_size; (void)ws_size;
    const float* lc  = (const float*)d_in[0];   // (8,2048,64)
    const float* knn = (const float*)d_in[1];   // (8,2048,32,64)
    const float* fB  = (const float*)d_in[2];   // (68,32)
    float* out = (float*)d_out;                 // (8,128,2048) f32
    char* ws = (char*)d_ws;
    double* part  = (double*)(ws + PART_OFF);
    float*  part2 = (float*)(ws + PART_OFF);
    float*  stdp  = (float*)(ws + STD_OFF);
    float*  invr  = (float*)(ws + INVR_OFF);
    float*  M     = (float*)(ws + M_OFF);

    hipLaunchKernelGGL(k1_partial, dim3(2048), dim3(256), 0, stream,
                       (const float4*)knn, (const float4*)lc, part);
    hipLaunchKernelGGL(k1_final, dim3(1), dim3(256), 0, stream, part, stdp);
    hipLaunchKernelGGL(k2_main, dim3(2048), dim3(256), 0, stream,
                       knn, lc, fB, stdp, M);
    hipLaunchKernelGGL(k3_part, dim3(128), dim3(256), 0, stream, M, part2);
    hipLaunchKernelGGL(k3_rfin, dim3(8), dim3(64), 0, stream, part2, invr);
    hipLaunchKernelGGL(k3_final, dim3(256), dim3(256), 0, stream, M, lc, invr, out);
}

// Round 9
// 99.711 us; speedup vs baseline: 1.0889x; 1.0102x over previous
//
#include <hip/hip_runtime.h>
#include <math.h>

// B=8, G=2048, K=32, N=64.
// Algebraic simplification (verified): e_x is constant along the K axis that
// up/down average over => k_anp_x = mean(ff,K) exactly; std_dev/p/nrm/lc/e_x
// branch is dead code. kl = 2*mean(ff,K); the norm over G cancels the 2.
// Everything feeding fourier_B is linear in 1/std => projection on RAW diffs,
// inv applied once at the end (sort order invariant under inv>0).
//
//  k1/k1f : global std(diff, ddof=1) (two-stage double reduce)
//  k2     : fB staged to LDS once (kills the per-chunk s_load stall);
//           per-wave quarter-streamed knn staging (64-B granule, double-buf,
//           counted vmcnt), row-keyed rotation, 68 @ fB(68x32) via
//           v_pk_fma_f32 with broadcast ds_read_b128 fB operands,
//           butterfly-compaction K-reduce, direct M store.
//  k3p/k3r: inv_r[b,c] = 1/||M[b,:,c]||_G  (coalesced 2-stage)
//  k3b    : out[b,c,g] = gelu(M*inv_r) - lc_line ; out[b,64+c,g] = lc_line

constexpr int Gg = 2048;

typedef float v2f __attribute__((ext_vector_type(2)));
typedef float v4f __attribute__((ext_vector_type(4)));

constexpr size_t PART_OFF = 0;       // k1: 2048*2 doubles; k3p: 128*64 f32
constexpr size_t STD_OFF  = 32768;   // 1 float
constexpr size_t INVR_OFF = 33024;   // 512 floats
constexpr size_t M_OFF    = 65536;   // 8*2048*64 floats = 4 MiB

// ---------------- K1: partial sums for global std ----------------
__global__ __launch_bounds__(256) void k1_partial(const float4* __restrict__ knn4,
                                                  const float4* __restrict__ lc4,
                                                  double* __restrict__ part)
{
    int tid  = threadIdx.x;
    int base = blockIdx.x * 256 + tid;
    float4 q[16];
    #pragma unroll
    for (int i = 0; i < 16; ++i) q[i] = knn4[base + i * 524288];
    double s = 0.0, s2 = 0.0;
    #pragma unroll
    for (int i = 0; i < 16; ++i) {
        int idx = base + i * 524288;
        float4 l = lc4[(idx >> 9) * 16 + (idx & 15)];
        float d0 = q[i].x - l.x, d1 = q[i].y - l.y, d2 = q[i].z - l.z, d3 = q[i].w - l.w;
        s += (double)d0; s += (double)d1; s += (double)d2; s += (double)d3;
        s2 = fma((double)d0, (double)d0, s2);
        s2 = fma((double)d1, (double)d1, s2);
        s2 = fma((double)d2, (double)d2, s2);
        s2 = fma((double)d3, (double)d3, s2);
    }
    __shared__ double sh[512];
    sh[tid] = s; sh[256 + tid] = s2;
    __syncthreads();
    for (int off = 128; off > 0; off >>= 1) {
        if (tid < off) { sh[tid] += sh[tid + off]; sh[256 + tid] += sh[256 + tid + off]; }
        __syncthreads();
    }
    if (tid == 0) { part[blockIdx.x * 2] = sh[0]; part[blockIdx.x * 2 + 1] = sh[256]; }
}

__global__ __launch_bounds__(256) void k1_final(const double* __restrict__ part,
                                                float* __restrict__ stdp)
{
    int tid = threadIdx.x;
    double s = 0.0, s2 = 0.0;
    for (int i = tid; i < 2048; i += 256) { s += part[2*i]; s2 += part[2*i+1]; }
    __shared__ double sh[512];
    sh[tid] = s; sh[256 + tid] = s2;
    __syncthreads();
    for (int off = 128; off > 0; off >>= 1) {
        if (tid < off) { sh[tid] += sh[tid + off]; sh[256 + tid] += sh[256 + tid + off]; }
        __syncthreads();
    }
    if (tid == 0) {
        double S = sh[0], S2 = sh[256];
        double Mn = 33554432.0;
        double var = (S2 - S * S / Mn) / (Mn - 1.0);
        stdp[0] = (float)sqrt(var);
    }
}

// ---------------- K2: main fused kernel ----------------
// Wave w owns rows 64w..64w+63. Quarter q = 4 chunks (64 B) of each row,
// double-buffered in qbuf[q&1] (4 KB/wave region). Rotation keyed on row
// (round-6 verified): slot t of row r holds chunk (t+k)&3, k = (r>>1)&3.
//   writer lane ls: row = ls>>2, slot = ls&3, src chunk = ((ls&3)+((ls>>3)&3))&3
//   reader row l, chunk jj: slot = (jj - ((l>>1)&3)) & 3
// fB lives in LDS (staged once, __syncthreads before any STAGE so vmcnt
// bookkeeping stays clean); per-chunk operands come from broadcast
// ds_read_b128 (uniform addr = conflict-free), removing the SMEM stall.
__global__ __launch_bounds__(256, 3) void k2_main(const float* __restrict__ knn,
                                                  const float* __restrict__ lc,
                                                  const float* __restrict__ fB,
                                                  const float* __restrict__ stdp,
                                                  float* __restrict__ M)
{
    __shared__ float4 qbuf[2][1024];   // [buf][w*256 + row*4 + slot]  32 KB
    __shared__ float4 lcs[8][16];      // 2 KB
    __shared__ float4 fBs4[544];       // 68*32 floats = 8.5 KB
    float* fBs = (float*)fBs4;

    const int tid = threadIdx.x;
    const int w   = tid >> 6;
    const int l   = tid & 63;
    const int grp = tid >> 5;
    const int key = (l >> 1) & 3;      // reader rotation key (row-keyed)

    // fB -> LDS once; barrier BEFORE any global_load_lds is issued.
    {
        float4* dst4 = (float4*)fBs4;
        const float4* src4 = (const float4*)fB;
        for (int i = tid; i < 544; i += 256) dst4[i] = src4[i];
    }
    __syncthreads();

    const char* gbase = (const char*)knn + (size_t)blockIdx.x * 65536;
    const char* wsrc  = gbase + (size_t)w * 16384
                      + (size_t)(l >> 2) * 256
                      + (size_t)((((l & 3) + ((l >> 3) & 3)) & 3) * 16);

    float4 lreg = make_float4(0.f, 0.f, 0.f, 0.f);
    if (l < 32)
        lreg = ((const float4*)lc)[(size_t)(blockIdx.x * 8 + 2 * w + (l >> 4)) * 16 + (l & 15)];

#define STAGE(q, buf)                                                          \
    {                                                                          \
        __builtin_amdgcn_global_load_lds((const void*)(wsrc + (q) * 64 +     0),\
            (void*)&qbuf[buf][w * 256 +   0], 16, 0, 0);                       \
        __builtin_amdgcn_global_load_lds((const void*)(wsrc + (q) * 64 +  4096),\
            (void*)&qbuf[buf][w * 256 +  64], 16, 0, 0);                       \
        __builtin_amdgcn_global_load_lds((const void*)(wsrc + (q) * 64 +  8192),\
            (void*)&qbuf[buf][w * 256 + 128], 16, 0, 0);                       \
        __builtin_amdgcn_global_load_lds((const void*)(wsrc + (q) * 64 + 12288),\
            (void*)&qbuf[buf][w * 256 + 192], 16, 0, 0);                       \
    }

    STAGE(0, 0)
    STAGE(1, 1)
    if (l < 32) lcs[2 * w + (l >> 4)][l & 15] = lreg;   // wave-private

    const float inv = 1.0f / (stdp[0] + 1e-5f);

    v2f acc2[16];
    #pragma unroll
    for (int c = 0; c < 16; ++c) acc2[c] = (v2f){0.0f, 0.0f};
    float dot = 0.0f;
    float kn0 = 0, kn1 = 0, kn2 = 0, ln0 = 0, ln1 = 0, ln2 = 0;

#define VMWAIT(n)  asm volatile("s_waitcnt vmcnt(" #n ")" ::: "memory");

// one feature row: 8 broadcast b128 reads + 16 pk_fma
#define FROW(base, ev)                                                        \
    {                                                                         \
        const v4f* fr4 = (const v4f*)(base);                                  \
        _Pragma("unroll")                                                     \
        for (int c4 = 0; c4 < 8; ++c4) {                                      \
            v4f t = fr4[c4];                                                  \
            acc2[2*c4]   = __builtin_elementwise_fma(ev, t.xy, acc2[2*c4]);   \
            acc2[2*c4+1] = __builtin_elementwise_fma(ev, t.zw, acc2[2*c4+1]); \
        }                                                                     \
    }

#define CHUNK(q, jj)                                                          \
    {                                                                         \
        float4 qv = qbuf[(q) & 1][w * 256 + l * 4 + (((jj) - key) & 3)];      \
        float4 lv = lcs[grp][(q) * 4 + (jj)];                                 \
        float e0 = qv.x - lv.x, e1 = qv.y - lv.y,                             \
              e2 = qv.z - lv.z, e3 = qv.w - lv.w;                             \
        if ((q) == 0 && (jj) == 0) {                                          \
            kn0 = e0; kn1 = e1; kn2 = e2;                                     \
            ln0 = lv.x; ln1 = lv.y; ln2 = lv.z;                               \
        }                                                                     \
        dot = fmaf(e0, lv.x, dot); dot = fmaf(e1, lv.y, dot);                 \
        dot = fmaf(e2, lv.z, dot); dot = fmaf(e3, lv.w, dot);                 \
        const float* fr = fBs + ((q) * 4 + (jj)) * 128;                       \
        FROW(fr,       ((v2f){e0, e0}))                                       \
        FROW(fr +  32, ((v2f){e1, e1}))                                       \
        FROW(fr +  64, ((v2f){e2, e2}))                                       \
        FROW(fr +  96, ((v2f){e3, e3}))                                       \
    }

    VMWAIT(4)                                   // quarter 0 landed
    CHUNK(0, 0) CHUNK(0, 1) CHUNK(0, 2) CHUNK(0, 3)
    STAGE(2, 0)
    VMWAIT(4)                                   // quarter 1 landed
    CHUNK(1, 0) CHUNK(1, 1) CHUNK(1, 2) CHUNK(1, 3)
    STAGE(3, 1)
    VMWAIT(4)                                   // quarter 2 landed
    CHUNK(2, 0) CHUNK(2, 1) CHUNK(2, 2) CHUNK(2, 3)
    VMWAIT(0)                                   // quarter 3 landed
    CHUNK(3, 0) CHUNK(3, 1) CHUNK(3, 2) CHUNK(3, 3)

#undef CHUNK
#undef VMWAIT
#undef STAGE

    // descending sort3 of raw d[0:3] and lc[0:3] (inv>0 preserves order)
    float a0 = kn0, a1 = kn1, a2 = kn2;
    float b0 = ln0, b1 = ln1, b2 = ln2;
    float t;
    if (a0 < a1) { t = a0; a0 = a1; a1 = t; }
    if (a1 < a2) { t = a1; a1 = a2; a2 = t; }
    if (a0 < a1) { t = a0; a0 = a1; a1 = t; }
    if (b0 < b1) { t = b0; b0 = b1; b1 = t; }
    if (b1 < b2) { t = b1; b1 = b2; b2 = t; }
    if (b0 < b1) { t = b0; b0 = b1; b1 = t; }

    float cr0 = a1 * b2 - a2 * b1;     // raw cross; inv scales through
    float cr1 = a2 * b0 - a0 * b2;
    float cr2 = a0 * b1 - a1 * b0;
    {
        const float* fr = fBs + 64 * 32;
        FROW(fr,       ((v2f){cr0, cr0}))
        FROW(fr +  32, ((v2f){cr1, cr1}))
        FROW(fr +  64, ((v2f){cr2, cr2}))
        FROW(fr +  96, ((v2f){dot, dot}))
    }
#undef FROW

    // phase = inv*acc revolutions; exact reduction r = a - rint(a); hw sin/cos
    const float* acc = (const float*)acc2;      // acc[i] = column i
    float vs[32], vc[32];
    #pragma unroll
    for (int c = 0; c < 32; ++c) {
        float a = acc[c] * inv;
        float r = a - rintf(a);
        vs[c] = __builtin_amdgcn_sinf(r);
        vc[c] = __builtin_amdgcn_cosf(r);
    }

    // butterfly-compaction reduce over the 32 K-lanes; lane ends holding the
    // full K-sum for column c = lane&31.
    float s1[16], c1[16];
    #pragma unroll
    for (int j = 0; j < 16; ++j) {
        float ea = vs[2*j]   + __shfl_xor(vs[2*j],   1);
        float eb = vs[2*j+1] + __shfl_xor(vs[2*j+1], 1);
        s1[j] = (tid & 1) ? eb : ea;
        float fa = vc[2*j]   + __shfl_xor(vc[2*j],   1);
        float fb = vc[2*j+1] + __shfl_xor(vc[2*j+1], 1);
        c1[j] = (tid & 1) ? fb : fa;
    }
    float s2[8], c2[8];
    #pragma unroll
    for (int j = 0; j < 8; ++j) {
        float ea = s1[2*j]   + __shfl_xor(s1[2*j],   2);
        float eb = s1[2*j+1] + __shfl_xor(s1[2*j+1], 2);
        s2[j] = (tid & 2) ? eb : ea;
        float fa = c1[2*j]   + __shfl_xor(c1[2*j],   2);
        float fb = c1[2*j+1] + __shfl_xor(c1[2*j+1], 2);
        c2[j] = (tid & 2) ? fb : fa;
    }
    float s3[4], c3[4];
    #pragma unroll
    for (int j = 0; j < 4; ++j) {
        float ea = s2[2*j]   + __shfl_xor(s2[2*j],   4);
        float eb = s2[2*j+1] + __shfl_xor(s2[2*j+1], 4);
        s3[j] = (tid & 4) ? eb : ea;
        float fa = c2[2*j]   + __shfl_xor(c2[2*j],   4);
        float fb = c2[2*j+1] + __shfl_xor(c2[2*j+1], 4);
        c3[j] = (tid & 4) ? fb : fa;
    }
    float s4[2], c4[2];
    #pragma unroll
    for (int j = 0; j < 2; ++j) {
        float ea = s3[2*j]   + __shfl_xor(s3[2*j],   8);
        float eb = s3[2*j+1] + __shfl_xor(s3[2*j+1], 8);
        s4[j] = (tid & 8) ? eb : ea;
        float fa = c3[2*j]   + __shfl_xor(c3[2*j],   8);
        float fb = c3[2*j+1] + __shfl_xor(c3[2*j+1], 8);
        c4[j] = (tid & 8) ? fb : fa;
    }
    float ea = s4[0] + __shfl_xor(s4[0], 16);
    float eb = s4[1] + __shfl_xor(s4[1], 16);
    float ssum = ((tid & 16) ? eb : ea) * (1.0f / 32.0f);
    float fa = c4[0] + __shfl_xor(c4[0], 16);
    float fb = c4[1] + __shfl_xor(c4[1], 16);
    float csum = ((tid & 16) ? fb : fa) * (1.0f / 32.0f);

    const int cc   = tid & 31;
    const int mrow = blockIdx.x * 8 + grp;      // = b*G+g
    M[(size_t)mrow * 64 + cc]      = ssum;
    M[(size_t)mrow * 64 + 32 + cc] = csum;
}

// ---------------- K3p: per-(b,gb) partial ssq over 128 g, coalesced ----------------
__global__ __launch_bounds__(256) void k3_part(const float* __restrict__ M,
                                               float* __restrict__ part2)
{
    int blk = blockIdx.x;                 // b*16 + gb
    int b = blk >> 4, gb = blk & 15;
    int t = threadIdx.x;
    int c = t & 63, gs = t >> 6;          // 0..3
    const float* base = M + ((size_t)(b * Gg + gb * 128 + gs)) * 64 + c;
    float ss = 0.0f;
    #pragma unroll
    for (int i = 0; i < 32; ++i) {        // g = gb*128 + gs + 4*i
        float v = base[(size_t)i * 256];
        ss = fmaf(v, v, ss);
    }
    __shared__ float sh[256];
    sh[t] = ss;
    __syncthreads();
    if (t < 64) part2[blk * 64 + t] = sh[t] + sh[t + 64] + sh[t + 128] + sh[t + 192];
}

__global__ __launch_bounds__(64) void k3_rfin(const float* __restrict__ part2,
                                              float* __restrict__ invr)
{
    int b = blockIdx.x, c = threadIdx.x;
    float s = 0.0f;
    #pragma unroll
    for (int gb = 0; gb < 16; ++gb) s += part2[(b * 16 + gb) * 64 + c];
    invr[b * 64 + c] = 1.0f / sqrtf(s);
}

// ---------------- K3b: finalize ----------------
__global__ __launch_bounds__(256) void k3_final(const float* __restrict__ M,
                                                const float* __restrict__ lc,
                                                const float* __restrict__ invr,
                                                float* __restrict__ out)
{
    __shared__ float mt[64][65];
    __shared__ float lt[64][65];
    __shared__ float ir[64];
    __shared__ float iln[64];
    int tid = threadIdx.x;
    int b  = blockIdx.x >> 5;
    int g0 = (blockIdx.x & 31) * 64;
    if (tid < 64) ir[tid] = invr[b * 64 + tid];
    const float* Mb = M  + ((size_t)(b * Gg + g0)) * 64;
    const float* Lb = lc + ((size_t)(b * Gg + g0)) * 64;
    #pragma unroll
    for (int i = 0; i < 4; ++i) {
        int f = i * 1024 + tid * 4;
        int r = f >> 6, col = f & 63;
        float4 mv = *(const float4*)(Mb + f);
        float4 lv = *(const float4*)(Lb + f);
        mt[r][col] = mv.x; mt[r][col+1] = mv.y; mt[r][col+2] = mv.z; mt[r][col+3] = mv.w;
        lt[r][col] = lv.x; lt[r][col+1] = lv.y; lt[r][col+2] = lv.z; lt[r][col+3] = lv.w;
    }
    __syncthreads();
    if (tid < 64) {
        float ss = 0.0f;
        #pragma unroll
        for (int c = 0; c < 64; ++c) { float v = lt[tid][c]; ss = fmaf(v, v, ss); }
        iln[tid] = 1.0f / sqrtf(ss);
    }
    __syncthreads();
    int gl = tid & 63;
    int c0 = tid >> 6;                    // 0..3, wave-uniform
    float il = iln[gl];
    int obase = (b * 128) * Gg + g0 + gl;
    #pragma unroll
    for (int i = 0; i < 16; ++i) {
        int c = c0 + i * 4;
        float lcl = lt[gl][c] * il;
        float x = mt[gl][c] * ir[c];
        float kl = 0.5f * x * (1.0f + erff(x * 0.70710678118654752f));
        out[obase + c * Gg]        = kl - lcl;   // line_element
        out[obase + (c + 64) * Gg] = lcl;        // lc_line
    }
}

extern "C" void kernel_launch(void* const* d_in, const int* in_sizes, int n_in,
                              void* d_out, int out_size, void* d_ws, size_t ws_size,
                              hipStream_t stream)
{
    (void)in_sizes; (void)n_in; (void)out_size; (void)ws_size;
    const float* lc  = (const float*)d_in[0];   // (8,2048,64)
    const float* knn = (const float*)d_in[1];   // (8,2048,32,64)
    const float* fB  = (const float*)d_in[2];   // (68,32)
    float* out = (float*)d_out;                 // (8,128,2048) f32
    char* ws = (char*)d_ws;
    double* part  = (double*)(ws + PART_OFF);
    float*  part2 = (float*)(ws + PART_OFF);
    float*  stdp  = (float*)(ws + STD_OFF);
    float*  invr  = (float*)(ws + INVR_OFF);
    float*  M     = (float*)(ws + M_OFF);

    hipLaunchKernelGGL(k1_partial, dim3(2048), dim3(256), 0, stream,
                       (const float4*)knn, (const float4*)lc, part);
    hipLaunchKernelGGL(k1_final, dim3(1), dim3(256), 0, stream, part, stdp);
    hipLaunchKernelGGL(k2_main, dim3(2048), dim3(256), 0, stream,
                       knn, lc, fB, stdp, M);
    hipLaunchKernelGGL(k3_part, dim3(128), dim3(256), 0, stream, M, part2);
    hipLaunchKernelGGL(k3_rfin, dim3(8), dim3(64), 0, stream, part2, invr);
    hipLaunchKernelGGL(k3_final, dim3(256), dim3(256), 0, stream, M, lc, invr, out);
}